// Round 4
// baseline (299.791 us; speedup 1.0000x reference)
//
#include <hip/hip_runtime.h>

// DeformableConvNet on MI355X — fp32 vector baseline.
// Stage 0: transpose weights for contiguous scalar (SGPR) loads.
// Stage 1: offset conv (N,18,H,W), channel-halved for 2 waves/SIMD.
// Stage 2: fused bilinear sample + einsum, o-halved (32 acc/thread).
//
// Design note: weight operands are wave-uniform -> indexed WITHOUT any
// threadIdx dependence so hipcc emits s_load + v_fma(SGPR). Avoids the
// LDS-broadcast-per-FMA bottleneck (per-CU LDS pipe ~6x too slow vs VALU).

#define HWSZ 16384  // H*W = 128*128
#define CIN  64
#define OUTC 64

__global__ __launch_bounds__(256) void prep_kernel(const float* __restrict__ w_off,
                                                   const float* __restrict__ w_def,
                                                   float* __restrict__ ws) {
    int i = blockIdx.x * 256 + threadIdx.x;
    // wofT[c*9+j][ch] (18 contiguous) at ws[0]
    if (i < 10368) {
        int cj = i / 18, ch = i % 18;
        ws[i] = w_off[ch * 576 + cj];
    }
    // wdT[kk][c][o] (64 contiguous) at ws[16384]
    if (i < 36864) {
        int kk = i >> 12, c = (i >> 6) & 63, o = i & 63;
        ws[16384 + i] = w_def[o * 576 + c * 9 + kk];
    }
}

__global__ __launch_bounds__(256) void offconv_kernel(const float* __restrict__ x,
                                                      const float* __restrict__ wofT,
                                                      const float* __restrict__ b_off,
                                                      float* __restrict__ off) {
    const int t = threadIdx.x;
    const int n = blockIdx.z >> 1;
    const int chbase = (blockIdx.z & 1) * 9;   // wave-uniform (blockIdx-derived)
    const int h = blockIdx.y * 16 + (t >> 4);
    const int w = blockIdx.x * 16 + (t & 15);

    // Precompute clamped gather offsets + validity masks for the 3x3 taps.
    int off9[9]; float msk9[9];
    #pragma unroll
    for (int kh = 0; kh < 3; ++kh) {
        #pragma unroll
        for (int kw = 0; kw < 3; ++kw) {
            int hy = h + kh - 1, wx = w + kw - 1;
            bool v = (hy >= 0) && (hy < 128) && (wx >= 0) && (wx < 128);
            int hc = hy < 0 ? 0 : (hy > 127 ? 127 : hy);
            int wc = wx < 0 ? 0 : (wx > 127 ? 127 : wx);
            off9[kh * 3 + kw] = hc * 128 + wc;
            msk9[kh * 3 + kw] = v ? 1.0f : 0.0f;
        }
    }

    float acc[9];
    #pragma unroll
    for (int cc = 0; cc < 9; ++cc) acc[cc] = b_off[chbase + cc];  // uniform s_load

    const float* xn = x + n * (CIN * HWSZ);
    for (int c = 0; c < CIN; ++c) {
        const float* xc = xn + c * HWSZ;
        float xv[9];
        #pragma unroll
        for (int j = 0; j < 9; ++j) xv[j] = xc[off9[j]] * msk9[j];
        const float* wr = wofT + c * 162 + chbase;  // uniform base
        #pragma unroll
        for (int j = 0; j < 9; ++j) {
            #pragma unroll
            for (int cc = 0; cc < 9; ++cc)
                acc[cc] = fmaf(xv[j], wr[j * 18 + cc], acc[cc]);
        }
    }

    float* op = off + n * (18 * HWSZ) + h * 128 + w;
    #pragma unroll
    for (int cc = 0; cc < 9; ++cc) op[(chbase + cc) * HWSZ] = acc[cc];
}

__global__ __launch_bounds__(256) void deform_kernel(const float* __restrict__ x,
                                                     const float* __restrict__ off,
                                                     const float* __restrict__ wdT,
                                                     const float* __restrict__ b_def,
                                                     float* __restrict__ out) {
    const int t = threadIdx.x;
    // o-half this thread owns; readfirstlane forces SGPR so weight loads scalarize
    const int gu = __builtin_amdgcn_readfirstlane(t >> 7);
    const int n = blockIdx.z;
    const int h = blockIdx.y * 8 + ((t >> 4) & 7);
    const int w = blockIdx.x * 16 + (t & 15);

    float acc[32];
    #pragma unroll
    for (int oo = 0; oo < 32; ++oo) acc[oo] = b_def[gu * 32 + oo];  // uniform s_load

    const float* xn = x + n * (CIN * HWSZ);
    const float* offn = off + n * (18 * HWSZ) + h * 128 + w;

    for (int kk = 0; kk < 9; ++kk) {
        float dy = offn[(2 * kk) * HWSZ];
        float dx = offn[(2 * kk + 1) * HWSZ];
        float py = (float)(h + (kk / 3) - 1) + dy;
        float px = (float)(w + (kk % 3) - 1) + dx;
        float y0f = floorf(py), x0f = floorf(px);
        float wy = py - y0f, wx = px - x0f;
        int y0 = (int)y0f, x0 = (int)x0f;
        int y1 = y0 + 1, x1 = x0 + 1;
        bool vy0 = (y0 >= 0) && (y0 < 128);
        bool vy1 = (y1 >= 0) && (y1 < 128);
        bool vx0 = (x0 >= 0) && (x0 < 128);
        bool vx1 = (x1 >= 0) && (x1 < 128);
        int cy0 = y0 < 0 ? 0 : (y0 > 127 ? 127 : y0);
        int cy1 = y1 < 0 ? 0 : (y1 > 127 ? 127 : y1);
        int cx0 = x0 < 0 ? 0 : (x0 > 127 ? 127 : x0);
        int cx1 = x1 < 0 ? 0 : (x1 > 127 ? 127 : x1);
        int i00 = cy0 * 128 + cx0;
        int i01 = cy0 * 128 + cx1;
        int i10 = cy1 * 128 + cx0;
        int i11 = cy1 * 128 + cx1;
        // fold per-corner validity into the bilinear coefficient
        float c00 = (vy0 && vx0) ? (1.f - wy) * (1.f - wx) : 0.f;
        float c01 = (vy0 && vx1) ? (1.f - wy) * wx : 0.f;
        float c10 = (vy1 && vx0) ? wy * (1.f - wx) : 0.f;
        float c11 = (vy1 && vx1) ? wy * wx : 0.f;

        const float* wk = wdT + kk * 4096 + gu * 32;  // uniform base
        #pragma unroll 2
        for (int c = 0; c < CIN; ++c) {
            const float* xc = xn + c * HWSZ;
            float s = c00 * xc[i00] + c01 * xc[i01] + c10 * xc[i10] + c11 * xc[i11];
            const float* wr = wk + c * 64;
            #pragma unroll
            for (int oo = 0; oo < 32; ++oo)
                acc[oo] = fmaf(s, wr[oo], acc[oo]);  // SGPR weight operand
        }
    }

    float* op = out + n * (OUTC * HWSZ) + h * 128 + w;
    #pragma unroll
    for (int oo = 0; oo < 32; ++oo) op[(gu * 32 + oo) * HWSZ] = acc[oo];
}

extern "C" void kernel_launch(void* const* d_in, const int* in_sizes, int n_in,
                              void* d_out, int out_size, void* d_ws, size_t ws_size,
                              hipStream_t stream) {
    const float* x     = (const float*)d_in[0];
    const float* w_off = (const float*)d_in[1];
    const float* b_off = (const float*)d_in[2];
    const float* w_def = (const float*)d_in[3];
    const float* b_def = (const float*)d_in[4];
    float* ws   = (float*)d_ws;
    float* wofT = ws;            // 10368 floats (padded region to 16384)
    float* wdT  = ws + 16384;    // 36864 floats
    float* off  = ws + 65536;    // 4*18*128*128 = 1179648 floats
    float* outp = (float*)d_out;

    prep_kernel<<<144, 256, 0, stream>>>(w_off, w_def, ws);
    offconv_kernel<<<dim3(8, 8, 8), 256, 0, stream>>>(x, wofT, b_off, off);
    deform_kernel<<<dim3(8, 16, 4), 256, 0, stream>>>(x, off, wdT, b_def, outp);
}

// Round 5
// 192.482 us; speedup vs baseline: 1.5575x; 1.5575x over previous
//
#include <hip/hip_runtime.h>

// DeformableConvNet v2 — NHWC layout + c-split blocks for occupancy.
// R4 counters showed v1 deform latency-bound: VALUBusy 27%, HBM 12.5%,
// occupancy 19% (2 waves/SIMD), FETCH 192MB (12x over-fetch from NCHW
// channel-striding). v2: transpose x to NHWC (contiguous c reads),
// c-quarter split per block (4 waves/SIMD), LDS tree reduction.

#define HWSZ 16384  // 128*128
#define CIN  64
#define OUTC 64

// ---------------- prep: weight transposes ----------------
__global__ __launch_bounds__(256) void prep_kernel(const float* __restrict__ w_off,
                                                   const float* __restrict__ w_def,
                                                   float* __restrict__ ws) {
    int i = blockIdx.x * 256 + threadIdx.x;
    // wofT[(c*9+j)][ch0..17] at ws[0]
    if (i < 10368) {
        int cj = i / 18, ch = i % 18;
        ws[i] = w_off[ch * 576 + cj];
    }
    // wdT[kk][c][o] at ws[16384]
    if (i < 36864) {
        int kk = i >> 12, c = (i >> 6) & 63, o = i & 63;
        ws[16384 + i] = w_def[o * 576 + c * 9 + kk];
    }
}

// ---------------- transpose x: NCHW -> NHWC ----------------
__global__ __launch_bounds__(256) void xpose_kernel(const float* __restrict__ x,
                                                    float* __restrict__ xT) {
    __shared__ float lds[64 * 129];  // +1 pad breaks bank aliasing
    const int h = blockIdx.x;
    const int n = blockIdx.y;
    const int t = threadIdx.x;
    for (int i = t; i < 8192; i += 256) {
        int c = i >> 7, w = i & 127;
        lds[c * 129 + w] = x[((size_t)(n * 64 + c) * 128 + h) * 128 + w];
    }
    __syncthreads();
    for (int i = t; i < 8192; i += 256) {
        int w = i >> 6, c = i & 63;
        xT[((size_t)(n * 128 + h) * 128 + w) * 64 + c] = lds[c * 129 + w];
    }
}

// ---------------- offset conv (NHWC in, (n,h,w,20) out) ----------------
__global__ __launch_bounds__(256) void offconv2_kernel(const float* __restrict__ xT,
                                                       const float* __restrict__ wofT,
                                                       const float* __restrict__ b_off,
                                                       float* __restrict__ off) {
    __shared__ float ldsA[64 * 19];
    __shared__ float ldsB[64 * 19];
    const int t = threadIdx.x;
    const int p = t & 63;
    const int cq = __builtin_amdgcn_readfirstlane(t >> 6);  // wave-uniform c-quarter
    const int n = blockIdx.z;
    const int h = blockIdx.y * 4 + (p >> 4);
    const int w = blockIdx.x * 16 + (p & 15);

    float acc[18];
#pragma unroll
    for (int ch = 0; ch < 18; ++ch) acc[ch] = 0.f;

    const float* xb = xT + (size_t)n * (HWSZ * 64) + cq * 16;

#pragma unroll 1
    for (int jy = 0; jy < 3; ++jy) {
#pragma unroll 1
        for (int jx = 0; jx < 3; ++jx) {
            int hy = h + jy - 1, wx = w + jx - 1;
            bool v = (hy >= 0) && (hy < 128) && (wx >= 0) && (wx < 128);
            int hc = min(max(hy, 0), 127), wc = min(max(wx, 0), 127);
            float m = v ? 1.f : 0.f;
            const float* src = xb + (hc * 128 + wc) * 64;
            float4 v0 = *(const float4*)(src);
            float4 v1 = *(const float4*)(src + 4);
            float4 v2 = *(const float4*)(src + 8);
            float4 v3 = *(const float4*)(src + 12);
            float xv[16] = {v0.x, v0.y, v0.z, v0.w, v1.x, v1.y, v1.z, v1.w,
                            v2.x, v2.y, v2.z, v2.w, v3.x, v3.y, v3.z, v3.w};
            const float* wr0 = wofT + ((cq * 16) * 9 + (jy * 3 + jx)) * 18;
#pragma unroll
            for (int ci = 0; ci < 16; ++ci) {
                float s = xv[ci] * m;
                const float* wr = wr0 + ci * 162;  // 9*18 per channel, uniform
#pragma unroll
                for (int ch = 0; ch < 18; ++ch)
                    acc[ch] = fmaf(s, wr[ch], acc[ch]);
            }
        }
    }

    // tree-reduce the 4 c-quarters: {2->A,3->B}; {0+=A,1+=B}; {1->A}; {0+=A,store}
    if (cq == 2) {
#pragma unroll
        for (int ch = 0; ch < 18; ++ch) ldsA[p * 19 + ch] = acc[ch];
    } else if (cq == 3) {
#pragma unroll
        for (int ch = 0; ch < 18; ++ch) ldsB[p * 19 + ch] = acc[ch];
    }
    __syncthreads();
    if (cq == 0) {
#pragma unroll
        for (int ch = 0; ch < 18; ++ch) acc[ch] += ldsA[p * 19 + ch];
    } else if (cq == 1) {
#pragma unroll
        for (int ch = 0; ch < 18; ++ch) acc[ch] += ldsB[p * 19 + ch];
    }
    __syncthreads();
    if (cq == 1) {
#pragma unroll
        for (int ch = 0; ch < 18; ++ch) ldsA[p * 19 + ch] = acc[ch];
    }
    __syncthreads();
    if (cq == 0) {
        float* op = off + ((size_t)(n * 128 + h) * 128 + w) * 20;
#pragma unroll
        for (int ch = 0; ch < 18; ++ch)
            op[ch] = acc[ch] + ldsA[p * 19 + ch] + b_off[ch];
    }
}

// ---------------- deformable conv (NHWC in, NCHW out) ----------------
__global__ __launch_bounds__(256, 4) void deform2_kernel(const float* __restrict__ xT,
                                                         const float* __restrict__ off,
                                                         const float* __restrict__ wdT,
                                                         const float* __restrict__ b_def,
                                                         float* __restrict__ out) {
    __shared__ float4 ldsA[64 * 17];  // 17-pad: float4 rows, conflict-light
    __shared__ float4 ldsB[64 * 17];
    const int t = threadIdx.x;
    const int p = t & 63;
    const int cq = __builtin_amdgcn_readfirstlane(t >> 6);
    const int n = blockIdx.z;
    const int h = blockIdx.y * 4 + (p >> 4);
    const int w = blockIdx.x * 16 + (p & 15);

    float acc[64] __attribute__((aligned(16)));
#pragma unroll
    for (int oo = 0; oo < 64; ++oo) acc[oo] = 0.f;

    const float* xb = xT + (size_t)n * (HWSZ * 64) + cq * 16;
    const float* ob = off + ((size_t)(n * 128 + h) * 128 + w) * 20;

#pragma unroll 1
    for (int ky = 0; ky < 3; ++ky) {
#pragma unroll 1
        for (int kx = 0; kx < 3; ++kx) {
            const int kk = ky * 3 + kx;
            float2 d = *(const float2*)(ob + 2 * kk);
            float py = (float)(h + ky - 1) + d.x;
            float px = (float)(w + kx - 1) + d.y;
            float y0f = floorf(py), x0f = floorf(px);
            float wy = py - y0f, wxf = px - x0f;
            int y0 = (int)y0f, x0 = (int)x0f;
            int y1 = y0 + 1, x1 = x0 + 1;
            bool vy0 = (y0 >= 0) && (y0 < 128);
            bool vy1 = (y1 >= 0) && (y1 < 128);
            bool vx0 = (x0 >= 0) && (x0 < 128);
            bool vx1 = (x1 >= 0) && (x1 < 128);
            int cy0 = min(max(y0, 0), 127), cy1 = min(max(y1, 0), 127);
            int cx0 = min(max(x0, 0), 127), cx1 = min(max(x1, 0), 127);
            float c00 = (vy0 && vx0) ? (1.f - wy) * (1.f - wxf) : 0.f;
            float c01 = (vy0 && vx1) ? (1.f - wy) * wxf : 0.f;
            float c10 = (vy1 && vx0) ? wy * (1.f - wxf) : 0.f;
            float c11 = (vy1 && vx1) ? wy * wxf : 0.f;

            const float* s00 = xb + (cy0 * 128 + cx0) * 64;
            const float* s01 = xb + (cy0 * 128 + cx1) * 64;
            const float* s10 = xb + (cy1 * 128 + cx0) * 64;
            const float* s11 = xb + (cy1 * 128 + cx1) * 64;
            const float* wk = wdT + (kk * 64 + cq * 16) * 64;  // uniform

#pragma unroll
            for (int j = 0; j < 4; ++j) {
                float4 a = *(const float4*)(s00 + 4 * j);
                float4 b = *(const float4*)(s01 + 4 * j);
                float4 c = *(const float4*)(s10 + 4 * j);
                float4 e = *(const float4*)(s11 + 4 * j);
                float s0 = fmaf(c00, a.x, fmaf(c01, b.x, fmaf(c10, c.x, c11 * e.x)));
                float s1 = fmaf(c00, a.y, fmaf(c01, b.y, fmaf(c10, c.y, c11 * e.y)));
                float s2 = fmaf(c00, a.z, fmaf(c01, b.z, fmaf(c10, c.z, c11 * e.z)));
                float s3 = fmaf(c00, a.w, fmaf(c01, b.w, fmaf(c10, c.w, c11 * e.w)));
                const float* wr = wk + (4 * j) * 64;  // uniform -> s_load
#pragma unroll
                for (int oo = 0; oo < 64; ++oo) acc[oo] = fmaf(s0, wr[oo], acc[oo]);
                wr += 64;
#pragma unroll
                for (int oo = 0; oo < 64; ++oo) acc[oo] = fmaf(s1, wr[oo], acc[oo]);
                wr += 64;
#pragma unroll
                for (int oo = 0; oo < 64; ++oo) acc[oo] = fmaf(s2, wr[oo], acc[oo]);
                wr += 64;
#pragma unroll
                for (int oo = 0; oo < 64; ++oo) acc[oo] = fmaf(s3, wr[oo], acc[oo]);
            }
        }
    }

    // tree-reduce c-quarters via LDS (float4 granularity)
    float4* a4 = (float4*)acc;
    if (cq == 2) {
#pragma unroll
        for (int i = 0; i < 16; ++i) ldsA[p * 17 + i] = a4[i];
    } else if (cq == 3) {
#pragma unroll
        for (int i = 0; i < 16; ++i) ldsB[p * 17 + i] = a4[i];
    }
    __syncthreads();
    if (cq == 0) {
#pragma unroll
        for (int i = 0; i < 16; ++i) {
            float4 v = ldsA[p * 17 + i];
            acc[4 * i] += v.x; acc[4 * i + 1] += v.y;
            acc[4 * i + 2] += v.z; acc[4 * i + 3] += v.w;
        }
    } else if (cq == 1) {
#pragma unroll
        for (int i = 0; i < 16; ++i) {
            float4 v = ldsB[p * 17 + i];
            acc[4 * i] += v.x; acc[4 * i + 1] += v.y;
            acc[4 * i + 2] += v.z; acc[4 * i + 3] += v.w;
        }
    }
    __syncthreads();
    if (cq == 1) {
#pragma unroll
        for (int i = 0; i < 16; ++i) ldsA[p * 17 + i] = a4[i];
    }
    __syncthreads();
    if (cq == 0) {
        float* op = out + (size_t)n * (OUTC * HWSZ) + h * 128 + w;
#pragma unroll
        for (int i = 0; i < 16; ++i) {
            float4 v = ldsA[p * 17 + i];
            op[(4 * i + 0) * HWSZ] = acc[4 * i + 0] + v.x + b_def[4 * i + 0];
            op[(4 * i + 1) * HWSZ] = acc[4 * i + 1] + v.y + b_def[4 * i + 1];
            op[(4 * i + 2) * HWSZ] = acc[4 * i + 2] + v.z + b_def[4 * i + 2];
            op[(4 * i + 3) * HWSZ] = acc[4 * i + 3] + v.w + b_def[4 * i + 3];
        }
    }
}

// ---------------- v1 fallback (if ws too small for NHWC copy) ----------------
__global__ __launch_bounds__(256) void offconv1_kernel(const float* __restrict__ x,
                                                       const float* __restrict__ wofT,
                                                       const float* __restrict__ b_off,
                                                       float* __restrict__ off) {
    const int t = threadIdx.x;
    const int n = blockIdx.z >> 1;
    const int chbase = (blockIdx.z & 1) * 9;
    const int h = blockIdx.y * 16 + (t >> 4);
    const int w = blockIdx.x * 16 + (t & 15);
    int off9[9]; float msk9[9];
#pragma unroll
    for (int kh = 0; kh < 3; ++kh)
#pragma unroll
        for (int kw = 0; kw < 3; ++kw) {
            int hy = h + kh - 1, wx = w + kw - 1;
            bool v = (hy >= 0) && (hy < 128) && (wx >= 0) && (wx < 128);
            int hc = min(max(hy, 0), 127), wc = min(max(wx, 0), 127);
            off9[kh * 3 + kw] = hc * 128 + wc;
            msk9[kh * 3 + kw] = v ? 1.0f : 0.0f;
        }
    float acc[9];
#pragma unroll
    for (int cc = 0; cc < 9; ++cc) acc[cc] = b_off[chbase + cc];
    const float* xn = x + n * (CIN * HWSZ);
    for (int c = 0; c < CIN; ++c) {
        const float* xc = xn + c * HWSZ;
        float xv[9];
#pragma unroll
        for (int j = 0; j < 9; ++j) xv[j] = xc[off9[j]] * msk9[j];
        const float* wr = wofT + c * 162 + chbase;
#pragma unroll
        for (int j = 0; j < 9; ++j)
#pragma unroll
            for (int cc = 0; cc < 9; ++cc)
                acc[cc] = fmaf(xv[j], wr[j * 18 + cc], acc[cc]);
    }
    float* op = off + n * (18 * HWSZ) + h * 128 + w;
#pragma unroll
    for (int cc = 0; cc < 9; ++cc) op[(chbase + cc) * HWSZ] = acc[cc];
}

__global__ __launch_bounds__(256) void deform1_kernel(const float* __restrict__ x,
                                                      const float* __restrict__ off,
                                                      const float* __restrict__ wdT,
                                                      const float* __restrict__ b_def,
                                                      float* __restrict__ out) {
    const int t = threadIdx.x;
    const int gu = __builtin_amdgcn_readfirstlane(t >> 7);
    const int n = blockIdx.z;
    const int h = blockIdx.y * 8 + ((t >> 4) & 7);
    const int w = blockIdx.x * 16 + (t & 15);
    float acc[32];
#pragma unroll
    for (int oo = 0; oo < 32; ++oo) acc[oo] = b_def[gu * 32 + oo];
    const float* xn = x + n * (CIN * HWSZ);
    const float* offn = off + n * (18 * HWSZ) + h * 128 + w;
    for (int kk = 0; kk < 9; ++kk) {
        float dy = offn[(2 * kk) * HWSZ];
        float dx = offn[(2 * kk + 1) * HWSZ];
        float py = (float)(h + (kk / 3) - 1) + dy;
        float px = (float)(w + (kk % 3) - 1) + dx;
        float y0f = floorf(py), x0f = floorf(px);
        float wy = py - y0f, wxf = px - x0f;
        int y0 = (int)y0f, x0 = (int)x0f;
        int y1 = y0 + 1, x1 = x0 + 1;
        bool vy0 = (y0 >= 0) && (y0 < 128), vy1 = (y1 >= 0) && (y1 < 128);
        bool vx0 = (x0 >= 0) && (x0 < 128), vx1 = (x1 >= 0) && (x1 < 128);
        int cy0 = min(max(y0, 0), 127), cy1 = min(max(y1, 0), 127);
        int cx0 = min(max(x0, 0), 127), cx1 = min(max(x1, 0), 127);
        int i00 = cy0 * 128 + cx0, i01 = cy0 * 128 + cx1;
        int i10 = cy1 * 128 + cx0, i11 = cy1 * 128 + cx1;
        float c00 = (vy0 && vx0) ? (1.f - wy) * (1.f - wxf) : 0.f;
        float c01 = (vy0 && vx1) ? (1.f - wy) * wxf : 0.f;
        float c10 = (vy1 && vx0) ? wy * (1.f - wxf) : 0.f;
        float c11 = (vy1 && vx1) ? wy * wxf : 0.f;
        const float* wk = wdT + kk * 4096 + gu * 32;
#pragma unroll 2
        for (int c = 0; c < CIN; ++c) {
            const float* xc = xn + c * HWSZ;
            float s = c00 * xc[i00] + c01 * xc[i01] + c10 * xc[i10] + c11 * xc[i11];
            const float* wr = wk + c * 64;
#pragma unroll
            for (int oo = 0; oo < 32; ++oo)
                acc[oo] = fmaf(s, wr[oo], acc[oo]);
        }
    }
    float* op = out + n * (OUTC * HWSZ) + h * 128 + w;
#pragma unroll
    for (int oo = 0; oo < 32; ++oo) op[(gu * 32 + oo) * HWSZ] = acc[oo];
}

extern "C" void kernel_launch(void* const* d_in, const int* in_sizes, int n_in,
                              void* d_out, int out_size, void* d_ws, size_t ws_size,
                              hipStream_t stream) {
    const float* x     = (const float*)d_in[0];
    const float* w_off = (const float*)d_in[1];
    const float* b_off = (const float*)d_in[2];
    const float* w_def = (const float*)d_in[3];
    const float* b_def = (const float*)d_in[4];
    float* ws   = (float*)d_ws;
    float* outp = (float*)d_out;

    // v2 ws layout: wofT[0..16384) | wdT[16384..53248) | xT (4.19M) | off20 (1.31M)
    const size_t need_v2 = (size_t)(16384 + 36864 + 4194304 + 1310720) * 4;
    if (ws_size >= need_v2) {
        float* wofT  = ws;
        float* wdT   = ws + 16384;
        float* xT    = ws + 53248;
        float* off20 = xT + 4194304;
        prep_kernel<<<144, 256, 0, stream>>>(w_off, w_def, ws);
        xpose_kernel<<<dim3(128, 4), 256, 0, stream>>>(x, xT);
        offconv2_kernel<<<dim3(8, 32, 4), 256, 0, stream>>>(xT, wofT, b_off, off20);
        deform2_kernel<<<dim3(8, 32, 4), 256, 0, stream>>>(xT, off20, wdT, b_def, outp);
    } else {
        float* wofT = ws;
        float* wdT  = ws + 16384;
        float* off  = ws + 65536;
        prep_kernel<<<144, 256, 0, stream>>>(w_off, w_def, ws);
        offconv1_kernel<<<dim3(8, 8, 8), 256, 0, stream>>>(x, wofT, b_off, off);
        deform1_kernel<<<dim3(8, 16, 4), 256, 0, stream>>>(x, off, wdT, b_def, outp);
    }
}

// Round 7
// 186.228 us; speedup vs baseline: 1.6098x; 1.0336x over previous
//
#include <hip/hip_runtime.h>

// DeformableConvNet v3 — deform einsum on MFMA (bf16 hi/lo split, fp32 acc).
// R5: deform2 VALU-busy time (43% x 91us = 39us) == fp32 FMA floor -> vector
// ALU is the wall, MfmaUtil was 0. v3 moves the 2.4G-MAC einsum to
// v_mfma_f32_32x32x16_bf16: wave = 32px x 64o, K=576 (9kk x 4 c-steps),
// 3 products (AhBh+AlBh+AhBl) for ~1e-5 abs error. Samples built per-lane
// in regs; weights pre-packed to per-lane frag order (k-perm cancels A/B).
// C/D layout per verified map: col=lane&31, row=(reg&3)+8*(reg>>2)+4*(lane>>5).
// Epilogue via +1-padded LDS for coalesced NCHW stores.

#define HWSZ 16384  // 128*128
#define CIN  64
#define OUTC 64

typedef __attribute__((ext_vector_type(8))) short short8v;
typedef __attribute__((ext_vector_type(16))) float f32x16;

static __device__ __forceinline__ unsigned bf16rne(float f) {
    unsigned u = __float_as_uint(f);
    return (u + 0x7FFFu + ((u >> 16) & 1u)) >> 16;
}

// ---------------- prep: wofT transpose + wB fragment packing ----------------
__global__ __launch_bounds__(256) void prep_kernel(const float* __restrict__ w_off,
                                                   const float* __restrict__ w_def,
                                                   float* __restrict__ ws) {
    int i = blockIdx.x * 256 + threadIdx.x;
    // wofT[(c*9+j)][ch0..17] at ws[0]
    if (i < 10368) {
        int cj = i / 18, ch = i % 18;
        ws[i] = w_off[ch * 576 + cj];
    }
    // wB: per-lane B-fragments for mfma_32x32x16_bf16, at ws[16384] (ushort).
    // flat i = ((s*2+ot)*2+hl)*512 + lane*8 + j ; s=kk*4+cq ; c=cq*16+hf*8+j ;
    // o = ot*32 + (lane&31) ; hl: 0=hi,1=lo residual.
    if (i < 73728) {
        unsigned short* wB = (unsigned short*)(ws + 16384);
        int j  = i & 7;
        int ln = (i >> 3) & 63;
        int hl = (i >> 9) & 1;
        int ot = (i >> 10) & 1;
        int s  = i >> 11;          // 0..35
        int kk = s >> 2, cq = s & 3;
        int hf = ln >> 5, r = ln & 31;
        int c  = cq * 16 + hf * 8 + j;
        int o  = ot * 32 + r;
        float wv = w_def[o * 576 + c * 9 + kk];
        unsigned hb = bf16rne(wv);
        if (hl == 0) {
            wB[i] = (unsigned short)hb;
        } else {
            float lo = wv - __uint_as_float(hb << 16);
            wB[i] = (unsigned short)bf16rne(lo);
        }
    }
}

// ---------------- transpose x: NCHW -> NHWC ----------------
__global__ __launch_bounds__(256) void xpose_kernel(const float* __restrict__ x,
                                                    float* __restrict__ xT) {
    __shared__ float lds[64 * 129];
    const int h = blockIdx.x;
    const int n = blockIdx.y;
    const int t = threadIdx.x;
    for (int i = t; i < 8192; i += 256) {
        int c = i >> 7, w = i & 127;
        lds[c * 129 + w] = x[((size_t)(n * 64 + c) * 128 + h) * 128 + w];
    }
    __syncthreads();
    for (int i = t; i < 8192; i += 256) {
        int w = i >> 6, c = i & 63;
        xT[((size_t)(n * 128 + h) * 128 + w) * 64 + c] = lds[c * 129 + w];
    }
}

// ---------------- offset conv (NHWC in, (n,h,w,20) out) — unchanged ----------------
__global__ __launch_bounds__(256) void offconv2_kernel(const float* __restrict__ xT,
                                                       const float* __restrict__ wofT,
                                                       const float* __restrict__ b_off,
                                                       float* __restrict__ off) {
    __shared__ float ldsA[64 * 19];
    __shared__ float ldsB[64 * 19];
    const int t = threadIdx.x;
    const int p = t & 63;
    const int cq = __builtin_amdgcn_readfirstlane(t >> 6);
    const int n = blockIdx.z;
    const int h = blockIdx.y * 4 + (p >> 4);
    const int w = blockIdx.x * 16 + (p & 15);

    float acc[18];
#pragma unroll
    for (int ch = 0; ch < 18; ++ch) acc[ch] = 0.f;

    const float* xb = xT + (size_t)n * (HWSZ * 64) + cq * 16;

#pragma unroll 1
    for (int jy = 0; jy < 3; ++jy) {
#pragma unroll 1
        for (int jx = 0; jx < 3; ++jx) {
            int hy = h + jy - 1, wx = w + jx - 1;
            bool v = (hy >= 0) && (hy < 128) && (wx >= 0) && (wx < 128);
            int hc = min(max(hy, 0), 127), wc = min(max(wx, 0), 127);
            float m = v ? 1.f : 0.f;
            const float* src = xb + (hc * 128 + wc) * 64;
            float4 v0 = *(const float4*)(src);
            float4 v1 = *(const float4*)(src + 4);
            float4 v2 = *(const float4*)(src + 8);
            float4 v3 = *(const float4*)(src + 12);
            float xv[16] = {v0.x, v0.y, v0.z, v0.w, v1.x, v1.y, v1.z, v1.w,
                            v2.x, v2.y, v2.z, v2.w, v3.x, v3.y, v3.z, v3.w};
            const float* wr0 = wofT + ((cq * 16) * 9 + (jy * 3 + jx)) * 18;
#pragma unroll
            for (int ci = 0; ci < 16; ++ci) {
                float s = xv[ci] * m;
                const float* wr = wr0 + ci * 162;
#pragma unroll
                for (int ch = 0; ch < 18; ++ch)
                    acc[ch] = fmaf(s, wr[ch], acc[ch]);
            }
        }
    }

    if (cq == 2) {
#pragma unroll
        for (int ch = 0; ch < 18; ++ch) ldsA[p * 19 + ch] = acc[ch];
    } else if (cq == 3) {
#pragma unroll
        for (int ch = 0; ch < 18; ++ch) ldsB[p * 19 + ch] = acc[ch];
    }
    __syncthreads();
    if (cq == 0) {
#pragma unroll
        for (int ch = 0; ch < 18; ++ch) acc[ch] += ldsA[p * 19 + ch];
    } else if (cq == 1) {
#pragma unroll
        for (int ch = 0; ch < 18; ++ch) acc[ch] += ldsB[p * 19 + ch];
    }
    __syncthreads();
    if (cq == 1) {
#pragma unroll
        for (int ch = 0; ch < 18; ++ch) ldsA[p * 19 + ch] = acc[ch];
    }
    __syncthreads();
    if (cq == 0) {
        float* op = off + ((size_t)(n * 128 + h) * 128 + w) * 20;
#pragma unroll
        for (int ch = 0; ch < 18; ++ch)
            op[ch] = acc[ch] + ldsA[p * 19 + ch] + b_off[ch];
    }
}

// ---------------- deformable conv: sampling + MFMA einsum ----------------
__global__ __launch_bounds__(256) void deform_mfma_kernel(
    const float* __restrict__ xT, const float* __restrict__ off20,
    const unsigned short* __restrict__ wB, const float* __restrict__ b_def,
    float* __restrict__ out) {
    __shared__ float lds[128 * 65];  // epilogue staging, +1 pad
    const int t = threadIdx.x;
    const int lane = t & 63;
    const int wv = t >> 6;        // 4 waves, each 32 px
    const int r = lane & 31;      // A row = pixel-in-strip ; C col = o-in-tile
    const int hf = lane >> 5;     // k-half
    const int h = blockIdx.x;
    const int n = blockIdx.y;
    const int w = wv * 32 + r;

    f32x16 acc0, acc1;
    const float bv0 = b_def[r], bv1 = b_def[32 + r];
#pragma unroll
    for (int i = 0; i < 16; ++i) { acc0[i] = bv0; acc1[i] = bv1; }

    const float* xb = xT + (size_t)n * (HWSZ * 64);
    const float* ob = off20 + ((size_t)(n * 128 + h) * 128 + w) * 20;
    const short8v* wb8 = (const short8v*)wB;

#pragma unroll 1
    for (int ky = 0; ky < 3; ++ky) {
#pragma unroll 1
        for (int kx = 0; kx < 3; ++kx) {
            const int kk = ky * 3 + kx;
            float2 d = *(const float2*)(ob + 2 * kk);
            float py  = (float)(h + ky - 1) + d.x;
            float pxx = (float)(w + kx - 1) + d.y;
            float y0f = floorf(py), x0f = floorf(pxx);
            float wy = py - y0f, wxf = pxx - x0f;
            int y0 = (int)y0f, x0 = (int)x0f;
            int y1 = y0 + 1, x1 = x0 + 1;
            bool vy0 = (y0 >= 0) && (y0 < 128), vy1 = (y1 >= 0) && (y1 < 128);
            bool vx0 = (x0 >= 0) && (x0 < 128), vx1 = (x1 >= 0) && (x1 < 128);
            int cy0 = min(max(y0, 0), 127), cy1 = min(max(y1, 0), 127);
            int cx0 = min(max(x0, 0), 127), cx1 = min(max(x1, 0), 127);
            float c00 = (vy0 && vx0) ? (1.f - wy) * (1.f - wxf) : 0.f;
            float c01 = (vy0 && vx1) ? (1.f - wy) * wxf : 0.f;
            float c10 = (vy1 && vx0) ? wy * (1.f - wxf) : 0.f;
            float c11 = (vy1 && vx1) ? wy * wxf : 0.f;
            const float* p00 = xb + (cy0 * 128 + cx0) * 64 + hf * 8;
            const float* p01 = xb + (cy0 * 128 + cx1) * 64 + hf * 8;
            const float* p10 = xb + (cy1 * 128 + cx0) * 64 + hf * 8;
            const float* p11 = xb + (cy1 * 128 + cx1) * 64 + hf * 8;

#pragma unroll
            for (int cq = 0; cq < 4; ++cq) {
                const int s = kk * 4 + cq;
                // B fragments (coalesced, address-independent -> early issue)
                short8v Bh0 = wb8[(s * 4 + 0) * 64 + lane];
                short8v Bl0 = wb8[(s * 4 + 1) * 64 + lane];
                short8v Bh1 = wb8[(s * 4 + 2) * 64 + lane];
                short8v Bl1 = wb8[(s * 4 + 3) * 64 + lane];
                const int c0 = cq * 16;
                float4 a0 = *(const float4*)(p00 + c0);
                float4 a1 = *(const float4*)(p00 + c0 + 4);
                float4 b0 = *(const float4*)(p01 + c0);
                float4 b1 = *(const float4*)(p01 + c0 + 4);
                float4 g0 = *(const float4*)(p10 + c0);
                float4 g1 = *(const float4*)(p10 + c0 + 4);
                float4 e0 = *(const float4*)(p11 + c0);
                float4 e1 = *(const float4*)(p11 + c0 + 4);
                float smp[8];
                smp[0] = c00 * a0.x + c01 * b0.x + c10 * g0.x + c11 * e0.x;
                smp[1] = c00 * a0.y + c01 * b0.y + c10 * g0.y + c11 * e0.y;
                smp[2] = c00 * a0.z + c01 * b0.z + c10 * g0.z + c11 * e0.z;
                smp[3] = c00 * a0.w + c01 * b0.w + c10 * g0.w + c11 * e0.w;
                smp[4] = c00 * a1.x + c01 * b1.x + c10 * g1.x + c11 * e1.x;
                smp[5] = c00 * a1.y + c01 * b1.y + c10 * g1.y + c11 * e1.y;
                smp[6] = c00 * a1.z + c01 * b1.z + c10 * g1.z + c11 * e1.z;
                smp[7] = c00 * a1.w + c01 * b1.w + c10 * g1.w + c11 * e1.w;
                short8v Ah, Al;
#pragma unroll
                for (int j2 = 0; j2 < 8; ++j2) {
                    unsigned hb = bf16rne(smp[j2]);
                    Ah[j2] = (short)hb;
                    float lo = smp[j2] - __uint_as_float(hb << 16);
                    Al[j2] = (short)bf16rne(lo);
                }
                acc0 = __builtin_amdgcn_mfma_f32_32x32x16_bf16(Ah, Bh0, acc0, 0, 0, 0);
                acc0 = __builtin_amdgcn_mfma_f32_32x32x16_bf16(Al, Bh0, acc0, 0, 0, 0);
                acc0 = __builtin_amdgcn_mfma_f32_32x32x16_bf16(Ah, Bl0, acc0, 0, 0, 0);
                acc1 = __builtin_amdgcn_mfma_f32_32x32x16_bf16(Ah, Bh1, acc1, 0, 0, 0);
                acc1 = __builtin_amdgcn_mfma_f32_32x32x16_bf16(Al, Bh1, acc1, 0, 0, 0);
                acc1 = __builtin_amdgcn_mfma_f32_32x32x16_bf16(Ah, Bl1, acc1, 0, 0, 0);
            }
        }
    }

    // epilogue: C/D row=(reg&3)+8*(reg>>2)+4*hf, col=r -> LDS -> coalesced NCHW
#pragma unroll
    for (int reg = 0; reg < 16; ++reg) {
        int rowpx = (reg & 3) + 8 * (reg >> 2) + 4 * hf;
        lds[(wv * 32 + rowpx) * 65 + r]      = acc0[reg];
        lds[(wv * 32 + rowpx) * 65 + 32 + r] = acc1[reg];
    }
    __syncthreads();
    float* op = out + ((size_t)(n * 64) * 128 + h) * 128;
#pragma unroll
    for (int it = 0; it < 32; ++it) {
        int idx = it * 256 + t;
        int o = idx >> 7, wc = idx & 127;
        op[(size_t)o * HWSZ + wc] = lds[wc * 65 + o];
    }
}

extern "C" void kernel_launch(void* const* d_in, const int* in_sizes, int n_in,
                              void* d_out, int out_size, void* d_ws, size_t ws_size,
                              hipStream_t stream) {
    const float* x     = (const float*)d_in[0];
    const float* w_off = (const float*)d_in[1];
    const float* b_off = (const float*)d_in[2];
    const float* w_def = (const float*)d_in[3];
    const float* b_def = (const float*)d_in[4];
    float* ws   = (float*)d_ws;
    float* outp = (float*)d_out;

    // ws: wofT[0,16384) | wB 73728 ushort = [16384,53248) | xT | off20
    float* wofT  = ws;
    unsigned short* wB = (unsigned short*)(ws + 16384);
    float* xT    = ws + 53248;
    float* off20 = xT + 4194304;

    prep_kernel<<<288, 256, 0, stream>>>(w_off, w_def, ws);
    xpose_kernel<<<dim3(128, 4), 256, 0, stream>>>(x, xT);
    offconv2_kernel<<<dim3(8, 32, 4), 256, 0, stream>>>(xT, wofT, b_off, off20);
    deform_mfma_kernel<<<dim3(128, 4), 256, 0, stream>>>(xT, off20, wB, b_def, outp);
}